// Round 4
// baseline (508.193 us; speedup 1.0000x reference)
//
#include <hip/hip_runtime.h>

#define BLOCK 256
#define DD 64
#define JJ 16

__device__ __forceinline__ float f4c(const float4& v, int i) {
    return i == 0 ? v.x : i == 1 ? v.y : i == 2 ? v.z : v.w;
}

__global__ __launch_bounds__(BLOCK, 4) void net_circuit_kernel(
    const float* __restrict__ x, const float* __restrict__ Ws,
    const float* __restrict__ bs, float* __restrict__ out, int B)
{
    // W slot map: slot(d) = (d&7)*8 + (d>>3).
    // Inner loop reads d = pass*32 + q*8 + d2  ->  slot = d2*8 + pass*4 + q:
    // quad addresses 64B apart -> 2-way per bank -> free (m136).
    __shared__ float Wl[DD * JJ];
    __shared__ __align__(16) float bsl[JJ];

    const int tid = threadIdx.x;
    for (int idx = tid; idx < DD * JJ; idx += BLOCK) {
        int d = idx >> 4, j = idx & 15;
        int slot = (d & 7) * 8 + (d >> 3);
        Wl[slot * JJ + j] = Ws[(j >> 2) * (DD * 4) + d * 4 + (j & 3)];
    }
    if (tid < JJ) bsl[tid] = bs[tid];
    __syncthreads();

    const int q  = tid & 3;          // quarter-of-pass this lane owns
    const int rr = (tid >> 2) & 15;  // row-within-group
    const int wid = tid >> 6;
    const long long wave_base = (long long)blockIdx.x * 256 + (long long)wid * 64;
    const bool full = (wave_base + 64 <= (long long)B);

    const float4* __restrict__ x4 = reinterpret_cast<const float4*>(x);
    const float4* __restrict__ W4 = reinterpret_cast<const float4*>(Wl);

    float acc[4][JJ];
    #pragma unroll
    for (int r = 0; r < 4; ++r)
        #pragma unroll
        for (int j = 0; j < JJ; ++j) acc[r][j] = 0.0f;

    // 2 passes (d-halves) x 2 row-halves: only 4 float4 of x live at a time
    // -> VGPR under the 128 step so __launch_bounds__(256,4) holds w/o spill.
    #pragma unroll
    for (int pass = 0; pass < 2; ++pass) {
        #pragma unroll
        for (int rh = 0; rh < 2; ++rh) {
            float4 xa[2], xb[2];
            #pragma unroll
            for (int rs = 0; rs < 2; ++rs) {
                const int r = rh * 2 + rs;
                long long row = wave_base + r * 16 + rr;
                if (full || row < (long long)B) {
                    long long bi = row * (DD / 4) + pass * 8 + q * 2;
                    xa[rs] = x4[bi];
                    xb[rs] = x4[bi + 1];
                } else {
                    xa[rs] = make_float4(0.f, 0.f, 0.f, 0.f);
                    xb[rs] = xa[rs];
                }
            }
            #pragma unroll
            for (int d2 = 0; d2 < 8; ++d2) {
                const int slot = d2 * 8 + pass * 4 + q;   // slot(d), d=pass*32+q*8+d2
                float4 w0 = W4[slot * 4 + 0];
                float4 w1 = W4[slot * 4 + 1];
                float4 w2 = W4[slot * 4 + 2];
                float4 w3 = W4[slot * 4 + 3];
                const float wf[JJ] = {w0.x, w0.y, w0.z, w0.w,
                                      w1.x, w1.y, w1.z, w1.w,
                                      w2.x, w2.y, w2.z, w2.w,
                                      w3.x, w3.y, w3.z, w3.w};
                #pragma unroll
                for (int rs = 0; rs < 2; ++rs) {
                    const int r = rh * 2 + rs;
                    float xs = (d2 < 4) ? f4c(xa[rs], d2) : f4c(xb[rs], d2 - 4);
                    #pragma unroll
                    for (int j = 0; j < JJ; ++j)
                        acc[r][j] = fmaf(xs, wf[j], acc[r][j]);
                }
            }
        }
    }

    // quad butterfly: every lane gets the full 64-d sum for all 4 row-groups
    #pragma unroll
    for (int r = 0; r < 4; ++r)
        #pragma unroll
        for (int j = 0; j < JJ; ++j) {
            float v = acc[r][j];
            v += __shfl_xor(v, 1, 64);
            v += __shfl_xor(v, 2, 64);
            acc[r][j] = v;
        }

    // lane q takes row-group r = q (static predicated select, no dyn indexing)
    float aj[JJ];
    #pragma unroll
    for (int j = 0; j < JJ; ++j) aj[j] = acc[0][j];
    #pragma unroll
    for (int r = 1; r < 4; ++r)
        #pragma unroll
        for (int j = 0; j < JJ; ++j)
            if (q == r) aj[j] = acc[r][j];

    float bl[JJ];
    #pragma unroll
    for (int g = 0; g < 4; ++g)
        reinterpret_cast<float4*>(bl)[g] = reinterpret_cast<const float4*>(bsl)[g];

    float h[JJ];
    #pragma unroll
    for (int j = 0; j < JJ; ++j) {
        float z = aj[j] + bl[j];
        h[j] = 1.0f / (1.0f + __expf(-z));
    }

    // f(17)=f(18)=1; i=16..1: neg_i=(i==3||i==7)?1:1-h[i-1]; f(i)=h*f(i+1)+neg*f(i+2)
    float f1 = 1.0f, f2 = 1.0f;
    #pragma unroll
    for (int i = JJ; i >= 1; --i) {
        float hj = h[i - 1];
        float neg = (i == 3 || i == 7) ? 1.0f : (1.0f - hj);
        float fi = fmaf(hj, f1, neg * f2);
        f2 = f1;
        f1 = fi;
    }

    long long orow = wave_base + q * 16 + rr;   // 64 consecutive rows per wave
    if (full || orow < (long long)B) out[orow] = f1;
}

extern "C" void kernel_launch(void* const* d_in, const int* in_sizes, int n_in,
                              void* d_out, int out_size, void* d_ws, size_t ws_size,
                              hipStream_t stream) {
    const float* x  = (const float*)d_in[0];
    const float* Ws = (const float*)d_in[1];
    const float* bs = (const float*)d_in[2];
    float* out = (float*)d_out;

    const int B = in_sizes[0] / DD;
    const int grid = (B + 255) / 256;

    net_circuit_kernel<<<grid, BLOCK, 0, stream>>>(x, Ws, bs, out, B);
}

// Round 5
// 60.813 us; speedup vs baseline: 8.3566x; 8.3566x over previous
//
#include <hip/hip_runtime.h>

#define BLOCK 256
#define DD 64
#define JJ 16

__device__ __forceinline__ float f4c(const float4& v, int i) {
    return i == 0 ? v.x : i == 1 ? v.y : i == 2 ? v.z : v.w;
}

// One row per thread. W/bias indices are threadIdx-independent -> uniform ->
// compiler emits s_load through the scalar K$ (4KB of W stays resident);
// FMAs take the W operand from SGPRs (1 SGPR read per VALU instr is legal).
// No LDS, no barriers, no cross-lane ops. ~60-70 VGPR by construction.
__global__ void net_circuit_kernel(
    const float* __restrict__ x, const float* __restrict__ Ws,
    const float* __restrict__ bs, float* __restrict__ out, int B)
{
    const long long row = (long long)blockIdx.x * BLOCK + threadIdx.x;
    if (row >= B) return;

    const float4* __restrict__ x4  = reinterpret_cast<const float4*>(x) + row * (DD / 4);
    const float4* __restrict__ Ws4 = reinterpret_cast<const float4*>(Ws);   // Ws4[n*64+d] = Ws[n][d][0..3]
    const float4* __restrict__ bs4 = reinterpret_cast<const float4*>(bs);

    float acc[JJ];
    #pragma unroll
    for (int j = 0; j < JJ; ++j) acc[j] = 0.0f;

    #pragma unroll
    for (int hf = 0; hf < 2; ++hf) {
        // grab the half-row (one 128B line per lane) in 8 adjacent loads
        float4 xv[8];
        #pragma unroll
        for (int c = 0; c < 8; ++c) xv[c] = x4[hf * 8 + c];

        #pragma unroll
        for (int c = 0; c < 8; ++c) {
            #pragma unroll
            for (int qq = 0; qq < 4; ++qq) {
                const int d = hf * 32 + c * 4 + qq;
                const float xs = f4c(xv[c], qq);
                #pragma unroll
                for (int n = 0; n < 4; ++n) {
                    const float4 w = Ws4[n * DD + d];   // uniform -> s_load_dwordx4
                    acc[n * 4 + 0] = fmaf(xs, w.x, acc[n * 4 + 0]);
                    acc[n * 4 + 1] = fmaf(xs, w.y, acc[n * 4 + 1]);
                    acc[n * 4 + 2] = fmaf(xs, w.z, acc[n * 4 + 2]);
                    acc[n * 4 + 3] = fmaf(xs, w.w, acc[n * 4 + 3]);
                }
            }
        }
    }

    float h[JJ];
    #pragma unroll
    for (int n = 0; n < 4; ++n) {
        const float4 b4 = bs4[n];   // uniform
        #pragma unroll
        for (int k = 0; k < 4; ++k) {
            float z = acc[n * 4 + k] + f4c(b4, k);
            h[n * 4 + k] = 1.0f / (1.0f + __expf(-z));
        }
    }

    // f(17)=f(18)=1; i=16..1: neg_i=(i==3||i==7)?1:1-h[i-1]; f(i)=h*f(i+1)+neg*f(i+2)
    float f1 = 1.0f, f2 = 1.0f;
    #pragma unroll
    for (int i = JJ; i >= 1; --i) {
        const float hj = h[i - 1];
        const float neg = (i == 3 || i == 7) ? 1.0f : (1.0f - hj);
        const float fi = fmaf(hj, f1, neg * f2);
        f2 = f1;
        f1 = fi;
    }

    out[row] = f1;
}

extern "C" void kernel_launch(void* const* d_in, const int* in_sizes, int n_in,
                              void* d_out, int out_size, void* d_ws, size_t ws_size,
                              hipStream_t stream) {
    const float* x  = (const float*)d_in[0];
    const float* Ws = (const float*)d_in[1];
    const float* bs = (const float*)d_in[2];
    float* out = (float*)d_out;

    const int B = in_sizes[0] / DD;
    const int grid = (B + BLOCK - 1) / BLOCK;

    net_circuit_kernel<<<grid, BLOCK, 0, stream>>>(x, Ws, bs, out, B);
}